// Round 17
// baseline (137.046 us; speedup 1.0000x reference)
//
#include <hip/hip_runtime.h>

#define N_NODES 100000
#define NDUMMY 100000   // dummy zero row index (padded table row)
#define NH 64
#define NB 500          // buckets
#define NPB 200         // nodes per bucket (500*200 = 100000 exactly); 200%8==0
#define BCAP 4096       // raw bucket capacity (avg 3200, +15.8 sigma)
#define PBCAP 6400      // padded bucket region (group-of-8 padding, 32/node cap)
#define EPB 8192        // edges per sort block -> 196 blocks, 1024 threads

// ---------------- bf16 helpers ----------------

__device__ __forceinline__ unsigned short f2bf(float f) {
    union { float f; unsigned int i; } c;
    c.f = f;
    unsigned int b = c.i;
    b += 0x7FFFu + ((b >> 16) & 1u);   // round to nearest even
    return (unsigned short)(b >> 16);
}

__device__ __forceinline__ unsigned pack2bf(float lo, float hi) {
    return (unsigned)f2bf(lo) | ((unsigned)f2bf(hi) << 16);
}

__device__ __forceinline__ float bfLO(unsigned u) {
    union { unsigned i; float f; } c; c.i = u << 16; return c.f;
}
__device__ __forceinline__ float bfHI(unsigned u) {
    union { unsigned i; float f; } c; c.i = u & 0xFFFF0000u; return c.f;
}

// ---------------- init: zero bucket cursors + dummy hs row ----------------

__global__ __launch_bounds__(512) void k_init(int* __restrict__ bcur, unsigned* __restrict__ dummy_row) {
    int t = threadIdx.x;
    if (t < NB) bcur[t] = 0;
    if (t < 32) dummy_row[t] = 0;   // 128B bf16 row of zeros
}

// ---------------- CSR build via block-local counting sort ----------------

__global__ __launch_bounds__(1024) void k_sort(const int* __restrict__ src, const int* __restrict__ dst,
                                               int* __restrict__ bcur, unsigned* __restrict__ ebuf, int e) {
    __shared__ unsigned sorted[EPB];        // 32KB
    __shared__ unsigned short cellof[EPB];  // 16KB
    __shared__ int lh[512];
    __shared__ int lbase[512];
    __shared__ int lcur[512];
    __shared__ int gpos[512];
    __shared__ int wsum[8];
    const int t = threadIdx.x;
    const int e0 = blockIdx.x * EPB;
    int cnt = e - e0; if (cnt > EPB) cnt = EPB;   // multiple of 4 (E%4==0)

    if (t < 512) lh[t] = 0;
    __syncthreads();

    for (int i = t * 4; i < cnt; i += 4096) {
        int4 d4 = *(const int4*)&dst[e0 + i];
        atomicAdd(&lh[d4.x / NPB], 1);
        atomicAdd(&lh[d4.y / NPB], 1);
        atomicAdd(&lh[d4.z / NPB], 1);
        atomicAdd(&lh[d4.w / NPB], 1);
    }
    __syncthreads();

    const int lane = t & 63, wave = t >> 6;
    int v = 0, inc = 0;
    if (t < 512) {
        v = (t < NB) ? lh[t] : 0;
        inc = v;
#pragma unroll
        for (int d = 1; d < 64; d <<= 1) {
            int u = __shfl_up(inc, d, 64);
            if (lane >= d) inc += u;
        }
        if (lane == 63) wsum[wave] = inc;
    }
    __syncthreads();
    if (t < NB) {
        int woff = 0;
#pragma unroll
        for (int w = 0; w < 8; ++w)
            if (w < wave) woff += wsum[w];
        const int excl = woff + inc - v;
        lbase[t] = excl;
        lcur[t] = excl;
        gpos[t] = atomicAdd(&bcur[t], v);
    }
    __syncthreads();

    for (int i = t * 4; i < cnt; i += 4096) {
        int4 d4 = *(const int4*)&dst[e0 + i];
        int4 s4 = *(const int4*)&src[e0 + i];
        int b0 = d4.x / NPB, b1 = d4.y / NPB, b2 = d4.z / NPB, b3 = d4.w / NPB;
        int p0 = atomicAdd(&lcur[b0], 1);
        int p1 = atomicAdd(&lcur[b1], 1);
        int p2 = atomicAdd(&lcur[b2], 1);
        int p3 = atomicAdd(&lcur[b3], 1);
        sorted[p0] = ((unsigned)(d4.x - b0 * NPB) << 17) | (unsigned)s4.x; cellof[p0] = (unsigned short)b0;
        sorted[p1] = ((unsigned)(d4.y - b1 * NPB) << 17) | (unsigned)s4.y; cellof[p1] = (unsigned short)b1;
        sorted[p2] = ((unsigned)(d4.z - b2 * NPB) << 17) | (unsigned)s4.z; cellof[p2] = (unsigned short)b2;
        sorted[p3] = ((unsigned)(d4.w - b3 * NPB) << 17) | (unsigned)s4.w; cellof[p3] = (unsigned short)b3;
    }
    __syncthreads();

    for (int i = t * 4; i < cnt; i += 4096) {
        uint4 sv = *(const uint4*)&sorted[i];
        ushort4 cv = *(const ushort4*)&cellof[i];
        int c0 = cv.x, c1 = cv.y, c2 = cv.z, c3 = cv.w;
        int g0 = gpos[c0] + (i + 0 - lbase[c0]);
        int g1 = gpos[c1] + (i + 1 - lbase[c1]);
        int g2 = gpos[c2] + (i + 2 - lbase[c2]);
        int g3 = gpos[c3] + (i + 3 - lbase[c3]);
        if (g0 < BCAP) ebuf[(long long)c0 * BCAP + g0] = sv.x;
        if (g1 < BCAP) ebuf[(long long)c1 * BCAP + g1] = sv.y;
        if (g2 < BCAP) ebuf[(long long)c2 * BCAP + g2] = sv.z;
        if (g3 < BCAP) ebuf[(long long)c3 * BCAP + g3] = sv.w;
    }
}

// one block per bucket: stage region in LDS, hist; pad each aligned GROUP OF 8
// nodes to the group-max degree (mult of 8); scatter into fixed csrc region.
__global__ __launch_bounds__(256) void k_build(const unsigned* __restrict__ ebuf, const int* __restrict__ bcur,
                                               int* __restrict__ rowptr, int* __restrict__ degp,
                                               float* __restrict__ dinv, int* __restrict__ csrc, int n) {
    __shared__ unsigned ls[BCAP];
    __shared__ int lh[256];
    __shared__ int lpv[256];
    __shared__ int lstart[256];
    __shared__ int lc[256];
    __shared__ int wsum[4];
    const int b = blockIdx.x;
    const int t = threadIdx.x;
    const int node0 = b * NPB;
    int count = bcur[b];
    if (count > BCAP) count = BCAP;
    const int rbase = b * PBCAP;

    lh[t] = 0;
    for (int i = t; i < count; i += 256) ls[i] = ebuf[(long long)b * BCAP + i];
    __syncthreads();
    for (int i = t; i < count; i += 256) atomicAdd(&lh[ls[i] >> 17], 1);
    __syncthreads();

    const int v = lh[t];
    lpv[t] = (v + 7) & ~7;
    __syncthreads();
    const int g = t & ~7;   // group of 8 (NPB%8==0 -> globally aligned)
    int pvg = lpv[g];
#pragma unroll
    for (int j = 1; j < 8; ++j) pvg = max(pvg, lpv[g + j]);

    const int lane = t & 63, wave = t >> 6;
    int inc = pvg;
#pragma unroll
    for (int d = 1; d < 64; d <<= 1) {
        int u = __shfl_up(inc, d, 64);
        if (lane >= d) inc += u;
    }
    if (lane == 63) wsum[wave] = inc;
    __syncthreads();
    int woff = 0;
#pragma unroll
    for (int w = 0; w < 4; ++w)
        if (w < wave) woff += wsum[w];
    const int start = rbase + woff + inc - pvg;

    lstart[t] = start;
    lc[t] = start;
    const int node = node0 + t;
    if (t < NPB && node < n) {
        rowptr[node] = start;
        degp[node] = pvg;
        dinv[node] = rsqrtf((float)(v + 1));   // +1 self loop
    }
    __syncthreads();

    for (int i = t; i < count; i += 256) {
        unsigned u = ls[i];
        int pos = atomicAdd(&lc[u >> 17], 1);
        csrc[pos] = (int)(u & 0x1FFFFu);
    }
    __syncthreads();

    const int pend = lstart[t] + pvg;
    for (int p = lc[t]; p < pend; ++p) csrc[p] = NDUMMY;
}

// ---------------- GEMM via MFMA: hs = bf16( (X @ W) * dinv ) ----------------
// Block = 256 thr (4 waves), tile 128 nodes x 64 cols.
// X staged in LDS as bf16 [128][K+8]. W staged in LDS as packed bf16 PAIRS
// wsb[c][k2] (u32 = {W[2k2][c], W[2k2+1][c]}), row stride padded to a 16B
// multiple so B-fragments are single b128 reads. B-frags read per-MFMA from
// LDS (no 64-VGPR resident W -> no register pressure / spill).
// Layouts (m89/m91-verified, R15-passed): A: row=lane&15, k=(lane>>4)*8+j;
// B: col=lane&15, same k; C/D: col=lane&15, row=(lane>>4)*4+reg.

typedef __attribute__((ext_vector_type(8))) short bf16x8;
typedef __attribute__((ext_vector_type(4))) float f32x4;

template <int K>
__global__ __launch_bounds__(256) void k_gemm_mfma(const float* __restrict__ X, const float* __restrict__ W,
                                                   const float* __restrict__ dinv,
                                                   unsigned short* __restrict__ out, int n) {
    constexpr int KP = K + 8;                 // 136 / 72 ushorts; row = 272B / 144B (16B mult)
    constexpr int KH = K / 2;                 // packed k2 range
    constexpr int WP = (K == 128) ? 68 : 40;  // wsb row stride u32 (272B / 160B, 16B mult)
    constexpr int NKS = K / 32;
    __shared__ unsigned short xs[128][KP];
    __shared__ unsigned wsb[64][WP];
    const int tid = threadIdx.x;
    const int lane = tid & 63;
    const int wv = tid >> 6;
    const int n0 = blockIdx.x * 128;
    const int col = lane & 15;
    const int q = lane >> 4;                  // 0..3
    const int krow = q * 8;

    // ---- stage X tile as bf16 (coalesced float4 reads, cvt, ushort4 writes)
    for (int idx = tid * 4; idx < 128 * K; idx += 1024) {
        int row = idx / K, c = idx % K;       // K pow2 -> shifts
        float4 v = make_float4(0.f, 0.f, 0.f, 0.f);
        if (n0 + row < n) v = *(const float4*)&X[(long long)(n0 + row) * K + c];
        ushort4 o;
        o.x = f2bf(v.x); o.y = f2bf(v.y); o.z = f2bf(v.z); o.w = f2bf(v.w);
        *(ushort4*)&xs[row][c] = o;
    }

    // ---- stage W as packed pairs: wsb[c][k2] = {W[2k2][c], W[2k2+1][c]}
    for (int idx = tid; idx < 64 * KH; idx += 256) {
        int c = idx & 63, k2 = idx >> 6;      // lane-consecutive c -> coalesced
        float w0 = W[(2 * k2) * NH + c];
        float w1 = W[(2 * k2 + 1) * NH + c];
        wsb[c][k2] = pack2bf(w0, w1);
    }
    __syncthreads();

    // ---- MFMA: 2 row-tiles x 4 col-tiles per wave; B-frag from LDS per use
    f32x4 zero = {0.f, 0.f, 0.f, 0.f};
    f32x4 acc[2][4];
#pragma unroll
    for (int mt = 0; mt < 2; ++mt)
#pragma unroll
        for (int nt = 0; nt < 4; ++nt) acc[mt][nt] = zero;

#pragma unroll
    for (int ks = 0; ks < NKS; ++ks) {
        bf16x8 b[4];
#pragma unroll
        for (int nt = 0; nt < 4; ++nt)
            b[nt] = *(const bf16x8*)&wsb[nt * 16 + col][ks * 16 + q * 4];
#pragma unroll
        for (int mt = 0; mt < 2; ++mt) {
            const int r = wv * 32 + mt * 16 + col;
            bf16x8 a = *(const bf16x8*)&xs[r][ks * 32 + krow];
#pragma unroll
            for (int nt = 0; nt < 4; ++nt)
                acc[mt][nt] = __builtin_amdgcn_mfma_f32_16x16x32_bf16(a, b[nt], acc[mt][nt], 0, 0, 0);
        }
    }

    // ---- epilogue: scale by dinv, cvt bf16, store
#pragma unroll
    for (int mt = 0; mt < 2; ++mt) {
#pragma unroll
        for (int r = 0; r < 4; ++r) {
            int node = n0 + wv * 32 + mt * 16 + q * 4 + r;
            if (node < n) {
                float dv = dinv[node];
#pragma unroll
                for (int nt = 0; nt < 4; ++nt)
                    out[(long long)node * NH + nt * 16 + col] = f2bf(acc[mt][nt][r] * dv);
            }
        }
    }
}

// ---------------- aggregation: 8 nodes/wave, lane loads uint4 (8 bf16 features) ----------

__global__ __launch_bounds__(256) void k_agg(const unsigned* __restrict__ hs32, const float* __restrict__ dinv,
                                             const int* __restrict__ rowptr, const int* __restrict__ degp,
                                             const int* __restrict__ csrc,
                                             const float* __restrict__ bias, const float* __restrict__ resid,
                                             float* __restrict__ out, int n) {
    const int gt = blockIdx.x * 256 + threadIdx.x;
    const int wave = gt >> 6;
    const int lane = threadIdx.x & 63;
    const int sub = lane >> 3;              // node within wave (0..7)
    const int li = lane & 7;                // uint4 index within row (features 8li..8li+7)
    const int node = wave * 8 + sub;
    if (node >= n) return;

    const uint4* hsv = (const uint4*)hs32;  // row = 8 uint4 = 128B
    uint4 su = hsv[node * 8 + li];          // self loop
    float a0 = bfLO(su.x), a1 = bfHI(su.x), a2 = bfLO(su.y), a3 = bfHI(su.y);
    float a4 = bfLO(su.z), a5 = bfHI(su.z), a6 = bfLO(su.w), a7 = bfHI(su.w);
    float b0 = 0.f, b1 = 0.f, b2 = 0.f, b3 = 0.f, b4 = 0.f, b5 = 0.f, b6 = 0.f, b7 = 0.f;

    const int rp = rowptr[node];
    const int dg = degp[node];              // same for all 8 nodes in group; mult of 8
    int4 c0, c1;
    if (dg > 0) {
        c0 = *(const int4*)&csrc[rp];
        c1 = *(const int4*)&csrc[rp + 4];
    }
    for (int e = 0; e < dg; e += 8) {
        const int4 m0 = c0, m1 = c1;
        if (e + 8 < dg) {                   // prefetch next iteration's indices
            c0 = *(const int4*)&csrc[rp + e + 8];
            c1 = *(const int4*)&csrc[rp + e + 12];
        }
        uint4 u0 = hsv[m0.x * 8 + li];
        uint4 u1 = hsv[m0.y * 8 + li];
        uint4 u2 = hsv[m0.z * 8 + li];
        uint4 u3 = hsv[m0.w * 8 + li];
        uint4 u4 = hsv[m1.x * 8 + li];
        uint4 u5 = hsv[m1.y * 8 + li];
        uint4 u6 = hsv[m1.z * 8 + li];
        uint4 u7 = hsv[m1.w * 8 + li];
        a0 += bfLO(u0.x); a1 += bfHI(u0.x); a2 += bfLO(u0.y); a3 += bfHI(u0.y);
        a4 += bfLO(u0.z); a5 += bfHI(u0.z); a6 += bfLO(u0.w); a7 += bfHI(u0.w);
        b0 += bfLO(u1.x); b1 += bfHI(u1.x); b2 += bfLO(u1.y); b3 += bfHI(u1.y);
        b4 += bfLO(u1.z); b5 += bfHI(u1.z); b6 += bfLO(u1.w); b7 += bfHI(u1.w);
        a0 += bfLO(u2.x); a1 += bfHI(u2.x); a2 += bfLO(u2.y); a3 += bfHI(u2.y);
        a4 += bfLO(u2.z); a5 += bfHI(u2.z); a6 += bfLO(u2.w); a7 += bfHI(u2.w);
        b0 += bfLO(u3.x); b1 += bfHI(u3.x); b2 += bfLO(u3.y); b3 += bfHI(u3.y);
        b4 += bfLO(u3.z); b5 += bfHI(u3.z); b6 += bfLO(u3.w); b7 += bfHI(u3.w);
        a0 += bfLO(u4.x); a1 += bfHI(u4.x); a2 += bfLO(u4.y); a3 += bfHI(u4.y);
        a4 += bfLO(u4.z); a5 += bfHI(u4.z); a6 += bfLO(u4.w); a7 += bfHI(u4.w);
        b0 += bfLO(u5.x); b1 += bfHI(u5.x); b2 += bfLO(u5.y); b3 += bfHI(u5.y);
        b4 += bfLO(u5.z); b5 += bfHI(u5.z); b6 += bfLO(u5.w); b7 += bfHI(u5.w);
        a0 += bfLO(u6.x); a1 += bfHI(u6.x); a2 += bfLO(u6.y); a3 += bfHI(u6.y);
        a4 += bfLO(u6.z); a5 += bfHI(u6.z); a6 += bfLO(u6.w); a7 += bfHI(u6.w);
        b0 += bfLO(u7.x); b1 += bfHI(u7.x); b2 += bfLO(u7.y); b3 += bfHI(u7.y);
        b4 += bfLO(u7.z); b5 += bfHI(u7.z); b6 += bfLO(u7.w); b7 += bfHI(u7.w);
    }
    const float dv = dinv[node];
    const float4 ba = *(const float4*)&bias[8 * li];
    const float4 bb = *(const float4*)&bias[8 * li + 4];
    float v0 = fmaxf(dv * (a0 + b0) + ba.x, 0.f);
    float v1 = fmaxf(dv * (a1 + b1) + ba.y, 0.f);
    float v2 = fmaxf(dv * (a2 + b2) + ba.z, 0.f);
    float v3 = fmaxf(dv * (a3 + b3) + ba.w, 0.f);
    float v4 = fmaxf(dv * (a4 + b4) + bb.x, 0.f);
    float v5 = fmaxf(dv * (a5 + b5) + bb.y, 0.f);
    float v6 = fmaxf(dv * (a6 + b6) + bb.z, 0.f);
    float v7 = fmaxf(dv * (a7 + b7) + bb.w, 0.f);
    const long long ob = (long long)node * NH + 8 * li;
    if (resid) {
        float4 r0 = *(const float4*)&resid[ob];
        float4 r1 = *(const float4*)&resid[ob + 4];
        v0 += r0.x; v1 += r0.y; v2 += r0.z; v3 += r0.w;
        v4 += r1.x; v5 += r1.y; v6 += r1.z; v7 += r1.w;
    }
    *(float4*)&out[ob] = make_float4(v0, v1, v2, v3);
    *(float4*)&out[ob + 4] = make_float4(v4, v5, v6, v7);
}

// ---------------- launch ----------------

extern "C" void kernel_launch(void* const* d_in, const int* in_sizes, int n_in,
                              void* d_out, int out_size, void* d_ws, size_t ws_size,
                              hipStream_t stream) {
    const float* x  = (const float*)d_in[0];
    const int*   ei = (const int*)d_in[1];
    const float* W1 = (const float*)d_in[2];
    const float* b1 = (const float*)d_in[3];
    const float* W2 = (const float*)d_in[4];
    const float* b2 = (const float*)d_in[5];
    float* out = (float*)d_out;

    const int N = N_NODES;
    const int E = in_sizes[1] / 2;
    const int* src = ei;
    const int* dst = ei + E;

    // workspace layout (element offsets, 16B-aligned; hs rows 128B-aligned).
    // hsb aliases ebuf: ebuf (8.19MB) dead after k_build; gemm1 overwrites it.
    // Dummy row NDUMMY at +12.8MB is beyond ebuf extent -> survives sort/build.
    const int NP = 100352;
    int*   bcur   = (int*)d_ws;                      // 512 (500 used)
    int*   rowptr = bcur + 512;                      // NP
    int*   degp   = rowptr + NP;                     // NP
    float* dinv   = (float*)(degp + NP);             // NP
    int*   csrc   = (int*)(dinv + NP);               // NB*PBCAP = 3.2M ints
    unsigned* ebuf = (unsigned*)(csrc + NB * PBCAP); // NB*BCAP u32 = 8.19MB
    unsigned* hs32 = ebuf;                           // packed bf16 [..][32] (aliases ebuf)
    unsigned short* hsb = (unsigned short*)hs32;
    float* h1     = (float*)(hs32 + (long long)(NDUMMY + 1) * 32);  // fp32 [N][64]

    const int nb_sort = (E + EPB - 1) / EPB;         // 196

    k_init<<<1, 512, 0, stream>>>(bcur, hs32 + (long long)NDUMMY * 32);
    k_sort<<<nb_sort, 1024, 0, stream>>>(src, dst, bcur, ebuf, E);
    k_build<<<NB, 256, 0, stream>>>(ebuf, bcur, rowptr, degp, dinv, csrc, N);

    // layer 1
    k_gemm_mfma<128><<<(N + 127) / 128, 256, 0, stream>>>(x, W1, dinv, hsb, N);
    k_agg<<<(N + 31) / 32, 256, 0, stream>>>(hs32, dinv, rowptr, degp, csrc, b1, nullptr, h1, N);

    // layer 2 (+ residual h1)
    k_gemm_mfma<64><<<(N + 127) / 128, 256, 0, stream>>>(h1, W2, dinv, hsb, N);
    k_agg<<<(N + 31) / 32, 256, 0, stream>>>(hs32, dinv, rowptr, degp, csrc, b2, h1, out, N);
}

// Round 18
// 131.275 us; speedup vs baseline: 1.0440x; 1.0440x over previous
//
#include <hip/hip_runtime.h>

#define N_NODES 100000
#define NDUMMY 100000   // dummy zero row index (padded table row)
#define NH 64
#define NB 500          // buckets
#define NPB 200         // nodes per bucket (500*200 = 100000 exactly); 200%8==0
#define BCAP 4096       // raw bucket capacity (avg 3200, +15.8 sigma)
#define PBCAP 6400      // padded bucket region (group-of-8 padding, 32/node cap)
#define EPB 8192        // edges per sort block -> 196 blocks, 1024 threads

// ---------------- bf16 helpers ----------------

__device__ __forceinline__ unsigned short f2bf(float f) {
    union { float f; unsigned int i; } c;
    c.f = f;
    unsigned int b = c.i;
    b += 0x7FFFu + ((b >> 16) & 1u);   // round to nearest even
    return (unsigned short)(b >> 16);
}

__device__ __forceinline__ unsigned pack2bf(float lo, float hi) {
    return (unsigned)f2bf(lo) | ((unsigned)f2bf(hi) << 16);
}

__device__ __forceinline__ float bfLO(unsigned u) {
    union { unsigned i; float f; } c; c.i = u << 16; return c.f;
}
__device__ __forceinline__ float bfHI(unsigned u) {
    union { unsigned i; float f; } c; c.i = u & 0xFFFF0000u; return c.f;
}

// ---------------- init: zero bucket cursors + dummy hs row ----------------

__global__ __launch_bounds__(512) void k_init(int* __restrict__ bcur, unsigned* __restrict__ dummy_row) {
    int t = threadIdx.x;
    if (t < NB) bcur[t] = 0;
    if (t < 32) dummy_row[t] = 0;   // 128B bf16 row of zeros
}

// ---------------- CSR build via block-local counting sort ----------------

__global__ __launch_bounds__(1024) void k_sort(const int* __restrict__ src, const int* __restrict__ dst,
                                               int* __restrict__ bcur, unsigned* __restrict__ ebuf, int e) {
    __shared__ unsigned sorted[EPB];        // 32KB
    __shared__ unsigned short cellof[EPB];  // 16KB
    __shared__ int lh[512];
    __shared__ int lbase[512];
    __shared__ int lcur[512];
    __shared__ int gpos[512];
    __shared__ int wsum[8];
    const int t = threadIdx.x;
    const int e0 = blockIdx.x * EPB;
    int cnt = e - e0; if (cnt > EPB) cnt = EPB;   // multiple of 4 (E%4==0)

    if (t < 512) lh[t] = 0;
    __syncthreads();

    for (int i = t * 4; i < cnt; i += 4096) {
        int4 d4 = *(const int4*)&dst[e0 + i];
        atomicAdd(&lh[d4.x / NPB], 1);
        atomicAdd(&lh[d4.y / NPB], 1);
        atomicAdd(&lh[d4.z / NPB], 1);
        atomicAdd(&lh[d4.w / NPB], 1);
    }
    __syncthreads();

    const int lane = t & 63, wave = t >> 6;
    int v = 0, inc = 0;
    if (t < 512) {
        v = (t < NB) ? lh[t] : 0;
        inc = v;
#pragma unroll
        for (int d = 1; d < 64; d <<= 1) {
            int u = __shfl_up(inc, d, 64);
            if (lane >= d) inc += u;
        }
        if (lane == 63) wsum[wave] = inc;
    }
    __syncthreads();
    if (t < NB) {
        int woff = 0;
#pragma unroll
        for (int w = 0; w < 8; ++w)
            if (w < wave) woff += wsum[w];
        const int excl = woff + inc - v;
        lbase[t] = excl;
        lcur[t] = excl;
        gpos[t] = atomicAdd(&bcur[t], v);
    }
    __syncthreads();

    for (int i = t * 4; i < cnt; i += 4096) {
        int4 d4 = *(const int4*)&dst[e0 + i];
        int4 s4 = *(const int4*)&src[e0 + i];
        int b0 = d4.x / NPB, b1 = d4.y / NPB, b2 = d4.z / NPB, b3 = d4.w / NPB;
        int p0 = atomicAdd(&lcur[b0], 1);
        int p1 = atomicAdd(&lcur[b1], 1);
        int p2 = atomicAdd(&lcur[b2], 1);
        int p3 = atomicAdd(&lcur[b3], 1);
        sorted[p0] = ((unsigned)(d4.x - b0 * NPB) << 17) | (unsigned)s4.x; cellof[p0] = (unsigned short)b0;
        sorted[p1] = ((unsigned)(d4.y - b1 * NPB) << 17) | (unsigned)s4.y; cellof[p1] = (unsigned short)b1;
        sorted[p2] = ((unsigned)(d4.z - b2 * NPB) << 17) | (unsigned)s4.z; cellof[p2] = (unsigned short)b2;
        sorted[p3] = ((unsigned)(d4.w - b3 * NPB) << 17) | (unsigned)s4.w; cellof[p3] = (unsigned short)b3;
    }
    __syncthreads();

    for (int i = t * 4; i < cnt; i += 4096) {
        uint4 sv = *(const uint4*)&sorted[i];
        ushort4 cv = *(const ushort4*)&cellof[i];
        int c0 = cv.x, c1 = cv.y, c2 = cv.z, c3 = cv.w;
        int g0 = gpos[c0] + (i + 0 - lbase[c0]);
        int g1 = gpos[c1] + (i + 1 - lbase[c1]);
        int g2 = gpos[c2] + (i + 2 - lbase[c2]);
        int g3 = gpos[c3] + (i + 3 - lbase[c3]);
        if (g0 < BCAP) ebuf[(long long)c0 * BCAP + g0] = sv.x;
        if (g1 < BCAP) ebuf[(long long)c1 * BCAP + g1] = sv.y;
        if (g2 < BCAP) ebuf[(long long)c2 * BCAP + g2] = sv.z;
        if (g3 < BCAP) ebuf[(long long)c3 * BCAP + g3] = sv.w;
    }
}

// one block per bucket: stage region in LDS, hist; pad each aligned GROUP OF 8
// nodes to the group-max degree (mult of 8); scatter into fixed csrc region.
__global__ __launch_bounds__(256) void k_build(const unsigned* __restrict__ ebuf, const int* __restrict__ bcur,
                                               int* __restrict__ rowptr, int* __restrict__ degp,
                                               float* __restrict__ dinv, int* __restrict__ csrc, int n) {
    __shared__ unsigned ls[BCAP];
    __shared__ int lh[256];
    __shared__ int lpv[256];
    __shared__ int lstart[256];
    __shared__ int lc[256];
    __shared__ int wsum[4];
    const int b = blockIdx.x;
    const int t = threadIdx.x;
    const int node0 = b * NPB;
    int count = bcur[b];
    if (count > BCAP) count = BCAP;
    const int rbase = b * PBCAP;

    lh[t] = 0;
    for (int i = t; i < count; i += 256) ls[i] = ebuf[(long long)b * BCAP + i];
    __syncthreads();
    for (int i = t; i < count; i += 256) atomicAdd(&lh[ls[i] >> 17], 1);
    __syncthreads();

    const int v = lh[t];
    lpv[t] = (v + 7) & ~7;
    __syncthreads();
    const int g = t & ~7;   // group of 8 (NPB%8==0 -> globally aligned)
    int pvg = lpv[g];
#pragma unroll
    for (int j = 1; j < 8; ++j) pvg = max(pvg, lpv[g + j]);

    const int lane = t & 63, wave = t >> 6;
    int inc = pvg;
#pragma unroll
    for (int d = 1; d < 64; d <<= 1) {
        int u = __shfl_up(inc, d, 64);
        if (lane >= d) inc += u;
    }
    if (lane == 63) wsum[wave] = inc;
    __syncthreads();
    int woff = 0;
#pragma unroll
    for (int w = 0; w < 4; ++w)
        if (w < wave) woff += wsum[w];
    const int start = rbase + woff + inc - pvg;

    lstart[t] = start;
    lc[t] = start;
    const int node = node0 + t;
    if (t < NPB && node < n) {
        rowptr[node] = start;
        degp[node] = pvg;
        dinv[node] = rsqrtf((float)(v + 1));   // +1 self loop
    }
    __syncthreads();

    for (int i = t; i < count; i += 256) {
        unsigned u = ls[i];
        int pos = atomicAdd(&lc[u >> 17], 1);
        csrc[pos] = (int)(u & 0x1FFFFu);
    }
    __syncthreads();

    const int pend = lstart[t] + pvg;
    for (int p = lc[t]; p < pend; ++p) csrc[p] = NDUMMY;
}

// ---------------- GEMM via MFMA: hs = bf16( (X @ W) * dinv ) ----------------
// Block = 256 thr (4 waves), tile 64 nodes x 64 cols; wave owns 16 rows.
// A-fragments loaded DIRECTLY from global (no LDS stage, no tile barrier):
// lane reads rows n0+wv*16+col at k = ks*32+q*8 -> per 16-lane group this is
// 16 fully-consumed 128B lines per instruction. All NKS load-pairs issued
// before any use (deep MLP). X is L3-resident -> L3-class source BW.
// W staged in LDS as packed bf16 pairs (R17 layout, verified).
// Layouts (m89/m91-verified, R15/R17-passed): A: row=lane&15, k=q*8+j;
// B: col=lane&15, same k; C/D: col=lane&15, row=q*4+reg.

typedef __attribute__((ext_vector_type(8))) short bf16x8;
typedef __attribute__((ext_vector_type(4))) float f32x4;

template <int K>
__global__ __launch_bounds__(256) void k_gemm_mfma(const float* __restrict__ X, const float* __restrict__ W,
                                                   const float* __restrict__ dinv,
                                                   unsigned short* __restrict__ out, int n) {
    constexpr int KH = K / 2;                 // packed k2 range
    constexpr int WP = (K == 128) ? 68 : 40;  // wsb row stride u32 (272B/160B, 16B mult)
    constexpr int NKS = K / 32;
    __shared__ unsigned wsb[64][WP];
    const int tid = threadIdx.x;
    const int lane = tid & 63;
    const int wv = tid >> 6;
    const int n0 = blockIdx.x * 64;
    const int col = lane & 15;
    const int q = lane >> 4;                  // 0..3

    // ---- issue all A loads first (independent, deep MLP; no barrier needed)
    const int row = n0 + wv * 16 + col;
    const int rc = (row < n) ? row : (n - 1);   // clamp: garbage rows only feed OOB outputs
    const float* xp = X + (long long)rc * K + q * 8;
    float4 xa[NKS], xb[NKS];
#pragma unroll
    for (int ks = 0; ks < NKS; ++ks) {
        xa[ks] = *(const float4*)&xp[ks * 32];
        xb[ks] = *(const float4*)&xp[ks * 32 + 4];
    }

    // ---- stage W as packed pairs: wsb[c][k2] = {W[2k2][c], W[2k2+1][c]}
    for (int idx = tid; idx < 64 * KH; idx += 256) {
        int c = idx & 63, k2 = idx >> 6;      // lane-consecutive c -> coalesced
        wsb[c][k2] = pack2bf(W[(2 * k2) * NH + c], W[(2 * k2 + 1) * NH + c]);
    }

    // ---- convert A to bf16 fragments while W staging completes
    union FragU { bf16x8 v; unsigned u[4]; };
    bf16x8 afrag[NKS];
#pragma unroll
    for (int ks = 0; ks < NKS; ++ks) {
        FragU f;
        f.u[0] = pack2bf(xa[ks].x, xa[ks].y);
        f.u[1] = pack2bf(xa[ks].z, xa[ks].w);
        f.u[2] = pack2bf(xb[ks].x, xb[ks].y);
        f.u[3] = pack2bf(xb[ks].z, xb[ks].w);
        afrag[ks] = f.v;
    }
    __syncthreads();

    // ---- MFMA: 4 col-tiles, NKS k-steps
    f32x4 zero = {0.f, 0.f, 0.f, 0.f};
    f32x4 acc[4];
#pragma unroll
    for (int nt = 0; nt < 4; ++nt) acc[nt] = zero;

#pragma unroll
    for (int ks = 0; ks < NKS; ++ks) {
#pragma unroll
        for (int nt = 0; nt < 4; ++nt) {
            bf16x8 b = *(const bf16x8*)&wsb[nt * 16 + col][ks * 16 + q * 4];
            acc[nt] = __builtin_amdgcn_mfma_f32_16x16x32_bf16(afrag[ks], b, acc[nt], 0, 0, 0);
        }
    }

    // ---- epilogue: scale by dinv, cvt bf16, store
#pragma unroll
    for (int r = 0; r < 4; ++r) {
        int node = n0 + wv * 16 + q * 4 + r;
        if (node < n) {
            float dv = dinv[node];
#pragma unroll
            for (int nt = 0; nt < 4; ++nt)
                out[(long long)node * NH + nt * 16 + col] = f2bf(acc[nt][r] * dv);
        }
    }
}

// ---------------- aggregation: 8 nodes/wave, lane loads uint4 (8 bf16 features) ----------

__global__ __launch_bounds__(256) void k_agg(const unsigned* __restrict__ hs32, const float* __restrict__ dinv,
                                             const int* __restrict__ rowptr, const int* __restrict__ degp,
                                             const int* __restrict__ csrc,
                                             const float* __restrict__ bias, const float* __restrict__ resid,
                                             float* __restrict__ out, int n) {
    const int gt = blockIdx.x * 256 + threadIdx.x;
    const int wave = gt >> 6;
    const int lane = threadIdx.x & 63;
    const int sub = lane >> 3;              // node within wave (0..7)
    const int li = lane & 7;                // uint4 index within row (features 8li..8li+7)
    const int node = wave * 8 + sub;
    if (node >= n) return;

    const uint4* hsv = (const uint4*)hs32;  // row = 8 uint4 = 128B
    uint4 su = hsv[node * 8 + li];          // self loop
    float a0 = bfLO(su.x), a1 = bfHI(su.x), a2 = bfLO(su.y), a3 = bfHI(su.y);
    float a4 = bfLO(su.z), a5 = bfHI(su.z), a6 = bfLO(su.w), a7 = bfHI(su.w);
    float b0 = 0.f, b1 = 0.f, b2 = 0.f, b3 = 0.f, b4 = 0.f, b5 = 0.f, b6 = 0.f, b7 = 0.f;

    const int rp = rowptr[node];
    const int dg = degp[node];              // same for all 8 nodes in group; mult of 8
    int4 c0, c1;
    if (dg > 0) {
        c0 = *(const int4*)&csrc[rp];
        c1 = *(const int4*)&csrc[rp + 4];
    }
    for (int e = 0; e < dg; e += 8) {
        const int4 m0 = c0, m1 = c1;
        if (e + 8 < dg) {                   // prefetch next iteration's indices
            c0 = *(const int4*)&csrc[rp + e + 8];
            c1 = *(const int4*)&csrc[rp + e + 12];
        }
        uint4 u0 = hsv[m0.x * 8 + li];
        uint4 u1 = hsv[m0.y * 8 + li];
        uint4 u2 = hsv[m0.z * 8 + li];
        uint4 u3 = hsv[m0.w * 8 + li];
        uint4 u4 = hsv[m1.x * 8 + li];
        uint4 u5 = hsv[m1.y * 8 + li];
        uint4 u6 = hsv[m1.z * 8 + li];
        uint4 u7 = hsv[m1.w * 8 + li];
        a0 += bfLO(u0.x); a1 += bfHI(u0.x); a2 += bfLO(u0.y); a3 += bfHI(u0.y);
        a4 += bfLO(u0.z); a5 += bfHI(u0.z); a6 += bfLO(u0.w); a7 += bfHI(u0.w);
        b0 += bfLO(u1.x); b1 += bfHI(u1.x); b2 += bfLO(u1.y); b3 += bfHI(u1.y);
        b4 += bfLO(u1.z); b5 += bfHI(u1.z); b6 += bfLO(u1.w); b7 += bfHI(u1.w);
        a0 += bfLO(u2.x); a1 += bfHI(u2.x); a2 += bfLO(u2.y); a3 += bfHI(u2.y);
        a4 += bfLO(u2.z); a5 += bfHI(u2.z); a6 += bfLO(u2.w); a7 += bfHI(u2.w);
        b0 += bfLO(u3.x); b1 += bfHI(u3.x); b2 += bfLO(u3.y); b3 += bfHI(u3.y);
        b4 += bfLO(u3.z); b5 += bfHI(u3.z); b6 += bfLO(u3.w); b7 += bfHI(u3.w);
        a0 += bfLO(u4.x); a1 += bfHI(u4.x); a2 += bfLO(u4.y); a3 += bfHI(u4.y);
        a4 += bfLO(u4.z); a5 += bfHI(u4.z); a6 += bfLO(u4.w); a7 += bfHI(u4.w);
        b0 += bfLO(u5.x); b1 += bfHI(u5.x); b2 += bfLO(u5.y); b3 += bfHI(u5.y);
        b4 += bfLO(u5.z); b5 += bfHI(u5.z); b6 += bfLO(u5.w); b7 += bfHI(u5.w);
        a0 += bfLO(u6.x); a1 += bfHI(u6.x); a2 += bfLO(u6.y); a3 += bfHI(u6.y);
        a4 += bfLO(u6.z); a5 += bfHI(u6.z); a6 += bfLO(u6.w); a7 += bfHI(u6.w);
        b0 += bfLO(u7.x); b1 += bfHI(u7.x); b2 += bfLO(u7.y); b3 += bfHI(u7.y);
        b4 += bfLO(u7.z); b5 += bfHI(u7.z); b6 += bfLO(u7.w); b7 += bfHI(u7.w);
    }
    const float dv = dinv[node];
    const float4 ba = *(const float4*)&bias[8 * li];
    const float4 bb = *(const float4*)&bias[8 * li + 4];
    float v0 = fmaxf(dv * (a0 + b0) + ba.x, 0.f);
    float v1 = fmaxf(dv * (a1 + b1) + ba.y, 0.f);
    float v2 = fmaxf(dv * (a2 + b2) + ba.z, 0.f);
    float v3 = fmaxf(dv * (a3 + b3) + ba.w, 0.f);
    float v4 = fmaxf(dv * (a4 + b4) + bb.x, 0.f);
    float v5 = fmaxf(dv * (a5 + b5) + bb.y, 0.f);
    float v6 = fmaxf(dv * (a6 + b6) + bb.z, 0.f);
    float v7 = fmaxf(dv * (a7 + b7) + bb.w, 0.f);
    const long long ob = (long long)node * NH + 8 * li;
    if (resid) {
        float4 r0 = *(const float4*)&resid[ob];
        float4 r1 = *(const float4*)&resid[ob + 4];
        v0 += r0.x; v1 += r0.y; v2 += r0.z; v3 += r0.w;
        v4 += r1.x; v5 += r1.y; v6 += r1.z; v7 += r1.w;
    }
    *(float4*)&out[ob] = make_float4(v0, v1, v2, v3);
    *(float4*)&out[ob + 4] = make_float4(v4, v5, v6, v7);
}

// ---------------- launch ----------------

extern "C" void kernel_launch(void* const* d_in, const int* in_sizes, int n_in,
                              void* d_out, int out_size, void* d_ws, size_t ws_size,
                              hipStream_t stream) {
    const float* x  = (const float*)d_in[0];
    const int*   ei = (const int*)d_in[1];
    const float* W1 = (const float*)d_in[2];
    const float* b1 = (const float*)d_in[3];
    const float* W2 = (const float*)d_in[4];
    const float* b2 = (const float*)d_in[5];
    float* out = (float*)d_out;

    const int N = N_NODES;
    const int E = in_sizes[1] / 2;
    const int* src = ei;
    const int* dst = ei + E;

    // workspace layout (element offsets, 16B-aligned; hs rows 128B-aligned).
    // hsb aliases ebuf: ebuf (8.19MB) dead after k_build; gemm1 overwrites it.
    // Dummy row NDUMMY at +12.8MB is beyond ebuf extent -> survives sort/build.
    const int NP = 100352;
    int*   bcur   = (int*)d_ws;                      // 512 (500 used)
    int*   rowptr = bcur + 512;                      // NP
    int*   degp   = rowptr + NP;                     // NP
    float* dinv   = (float*)(degp + NP);             // NP
    int*   csrc   = (int*)(dinv + NP);               // NB*PBCAP = 3.2M ints
    unsigned* ebuf = (unsigned*)(csrc + NB * PBCAP); // NB*BCAP u32 = 8.19MB
    unsigned* hs32 = ebuf;                           // packed bf16 [..][32] (aliases ebuf)
    unsigned short* hsb = (unsigned short*)hs32;
    float* h1     = (float*)(hs32 + (long long)(NDUMMY + 1) * 32);  // fp32 [N][64]

    const int nb_sort = (E + EPB - 1) / EPB;         // 196

    k_init<<<1, 512, 0, stream>>>(bcur, hs32 + (long long)NDUMMY * 32);
    k_sort<<<nb_sort, 1024, 0, stream>>>(src, dst, bcur, ebuf, E);
    k_build<<<NB, 256, 0, stream>>>(ebuf, bcur, rowptr, degp, dinv, csrc, N);

    // layer 1
    k_gemm_mfma<128><<<(N + 63) / 64, 256, 0, stream>>>(x, W1, dinv, hsb, N);
    k_agg<<<(N + 31) / 32, 256, 0, stream>>>(hs32, dinv, rowptr, degp, csrc, b1, nullptr, h1, N);

    // layer 2 (+ residual h1)
    k_gemm_mfma<64><<<(N + 63) / 64, 256, 0, stream>>>(h1, W2, dinv, hsb, N);
    k_agg<<<(N + 31) / 32, 256, 0, stream>>>(hs32, dinv, rowptr, degp, csrc, b2, h1, out, N);
}